// Round 1
// baseline (3008.126 us; speedup 1.0000x reference)
//
#include <hip/hip_runtime.h>
#include <math.h>

#define NN 100000
#define NE 1600000
#define NF 500
#define NH 128
#define NC 47
#define NL 8

// ---------------- graph preprocessing ----------------

__global__ void count_kernel(const int* __restrict__ dst, int* __restrict__ deg) {
    int e = blockIdx.x * 256 + threadIdx.x;
    if (e < NE) atomicAdd(&deg[dst[e]], 1);
}

__global__ void dinv_kernel(const int* __restrict__ deg, float* __restrict__ dinv) {
    int i = blockIdx.x * 256 + threadIdx.x;
    if (i < NN) dinv[i] = rsqrtf((float)(deg[i] + 1));  // +1 self loop
}

__global__ __launch_bounds__(1024) void scan_kernel(const int* __restrict__ deg,
                                                    int* __restrict__ rp) {
    __shared__ int s[1024];
    __shared__ int carry_s;
    int tid = threadIdx.x;
    if (tid == 0) carry_s = 0;
    __syncthreads();
    for (int base = 0; base < NN; base += 1024) {
        int i = base + tid;
        int v = (i < NN) ? deg[i] : 0;
        s[tid] = v;
        __syncthreads();
        for (int off = 1; off < 1024; off <<= 1) {
            int t = (tid >= off) ? s[tid - off] : 0;
            __syncthreads();
            s[tid] += t;
            __syncthreads();
        }
        int carry = carry_s;              // safe: last write was sync'd
        if (i < NN) rp[i] = carry + s[tid] - v;   // exclusive
        __syncthreads();
        if (tid == 1023) carry_s = carry + s[1023];
        __syncthreads();
    }
    if (tid == 0) rp[NN] = carry_s;
}

__global__ void fill_kernel(const int* __restrict__ src, const int* __restrict__ dst,
                            const float* __restrict__ dinv, int* __restrict__ cursor,
                            int* __restrict__ col, float* __restrict__ val) {
    int e = blockIdx.x * 256 + threadIdx.x;
    if (e < NE) {
        int s = src[e], d = dst[e];
        int pos = atomicAdd(&cursor[d], 1);
        col[pos] = s;
        val[pos] = dinv[s] * dinv[d];
    }
}

// ---------------- aggregation: z = 0.9 * (norm-adj @ h) + 0.1 * h0 ----------------

__global__ __launch_bounds__(128) void agg_kernel(const float* __restrict__ h,
                                                  const float* __restrict__ h0,
                                                  const float* __restrict__ dinv,
                                                  const int* __restrict__ rp,
                                                  const int* __restrict__ col,
                                                  const float* __restrict__ val,
                                                  float* __restrict__ z) {
    int i = blockIdx.x;
    int t = threadIdx.x;
    float di = dinv[i];
    float acc = di * di * h[(size_t)i * NH + t];  // self loop
    int e1 = rp[i + 1];
    for (int e = rp[i]; e < e1; ++e) {
        acc = fmaf(val[e], h[(size_t)col[e] * NH + t], acc);
    }
    z[(size_t)i * NH + t] = 0.9f * acc + 0.1f * h0[(size_t)i * NH + t];
}

// ---------------- dense GEMMs (f32 vector ALU) ----------------

// h = relu(x @ w0 + b0); also h0 = h
__global__ __launch_bounds__(256) void gemm_in(const float* __restrict__ x,
                                               const float* __restrict__ w0,
                                               const float* __restrict__ b0,
                                               float* __restrict__ h,
                                               float* __restrict__ h0v) {
    __shared__ float4 wl4[100 * 32];   // 100 k-rows x 128 cols
    int tid = threadIdx.x;
    int tc = tid & 31, tr = tid >> 5;
    int rbase = blockIdx.x * 32 + tr * 4;
    float acc[4][4] = {};
    for (int kb = 0; kb < NF; kb += 100) {
        __syncthreads();
        const float4* Wv = (const float4*)(w0 + (size_t)kb * NH);
        for (int idx = tid; idx < 3200; idx += 256) wl4[idx] = Wv[idx];
        __syncthreads();
        const float* xr = x + (size_t)rbase * NF + kb;
        for (int k = 0; k < 100; k += 4) {
            float4 a[4];
            #pragma unroll
            for (int j = 0; j < 4; ++j) a[j] = *(const float4*)(xr + j * NF + k);
            #pragma unroll
            for (int kk = 0; kk < 4; ++kk) {
                float4 w4 = wl4[(k + kk) * 32 + tc];
                #pragma unroll
                for (int j = 0; j < 4; ++j) {
                    float aj = (&a[j].x)[kk];
                    acc[j][0] = fmaf(aj, w4.x, acc[j][0]);
                    acc[j][1] = fmaf(aj, w4.y, acc[j][1]);
                    acc[j][2] = fmaf(aj, w4.z, acc[j][2]);
                    acc[j][3] = fmaf(aj, w4.w, acc[j][3]);
                }
            }
        }
    }
    #pragma unroll
    for (int j = 0; j < 4; ++j) {
        int r = rbase + j;
        float4 o;
        o.x = fmaxf(acc[j][0] + b0[tc * 4 + 0], 0.f);
        o.y = fmaxf(acc[j][1] + b0[tc * 4 + 1], 0.f);
        o.z = fmaxf(acc[j][2] + b0[tc * 4 + 2], 0.f);
        o.w = fmaxf(acc[j][3] + b0[tc * 4 + 3], 0.f);
        *(float4*)(h + (size_t)r * NH + tc * 4) = o;
        *(float4*)(h0v + (size_t)r * NH + tc * 4) = o;
    }
}

// out = relu((1-beta)*z + beta*(z @ W))
__global__ __launch_bounds__(256) void gemm_conv(const float* __restrict__ z,
                                                 const float* __restrict__ W,
                                                 float* __restrict__ out, float beta) {
    __shared__ float4 wl4[128 * 32];   // 64 KB
    int tid = threadIdx.x;
    const float4* Wv = (const float4*)W;
    #pragma unroll
    for (int i = 0; i < 16; ++i) wl4[tid + i * 256] = Wv[tid + i * 256];
    __syncthreads();
    int tc = tid & 31, tr = tid >> 5;
    int rbase = blockIdx.x * 32 + tr * 4;
    const float* zr = z + (size_t)rbase * NH;
    float acc[4][4] = {};
    for (int k = 0; k < 128; k += 4) {
        float4 a[4];
        #pragma unroll
        for (int j = 0; j < 4; ++j) a[j] = *(const float4*)(zr + j * NH + k);
        #pragma unroll
        for (int kk = 0; kk < 4; ++kk) {
            float4 w4 = wl4[(k + kk) * 32 + tc];
            #pragma unroll
            for (int j = 0; j < 4; ++j) {
                float aj = (&a[j].x)[kk];
                acc[j][0] = fmaf(aj, w4.x, acc[j][0]);
                acc[j][1] = fmaf(aj, w4.y, acc[j][1]);
                acc[j][2] = fmaf(aj, w4.z, acc[j][2]);
                acc[j][3] = fmaf(aj, w4.w, acc[j][3]);
            }
        }
    }
    float ob = 1.0f - beta;
    #pragma unroll
    for (int j = 0; j < 4; ++j) {
        int r = rbase + j;
        float4 zv = *(const float4*)(z + (size_t)r * NH + tc * 4);
        float4 o;
        o.x = fmaxf(ob * zv.x + beta * acc[j][0], 0.f);
        o.y = fmaxf(ob * zv.y + beta * acc[j][1], 0.f);
        o.z = fmaxf(ob * zv.z + beta * acc[j][2], 0.f);
        o.w = fmaxf(ob * zv.w + beta * acc[j][3], 0.f);
        *(float4*)(out + (size_t)r * NH + tc * 4) = o;
    }
}

// logits = h @ w1 + b1 ; out = log_softmax(logits)
__global__ __launch_bounds__(256) void out_kernel(const float* __restrict__ h,
                                                  const float* __restrict__ w1,
                                                  const float* __restrict__ b1,
                                                  float* __restrict__ out) {
    __shared__ float wl[NH * NC];
    int tid = threadIdx.x;
    for (int i = tid; i < NH * NC; i += 256) wl[i] = w1[i];
    __syncthreads();
    int wave = tid >> 6, lane = tid & 63;
    for (int r = blockIdx.x * 4 + wave; r < NN; r += gridDim.x * 4) {
        const float* hr = h + (size_t)r * NH;
        float acc = 0.f;
        if (lane < NC) {
            acc = b1[lane];
            for (int k = 0; k < NH; ++k) acc = fmaf(hr[k], wl[k * NC + lane], acc);
        }
        float logit = (lane < NC) ? acc : -INFINITY;
        float m = logit;
        #pragma unroll
        for (int off = 32; off > 0; off >>= 1) m = fmaxf(m, __shfl_xor(m, off));
        float e = expf(logit - m);    // lanes >= NC contribute exp(-inf) = 0
        float ssum = e;
        #pragma unroll
        for (int off = 32; off > 0; off >>= 1) ssum += __shfl_xor(ssum, off);
        float ls = logf(ssum);
        if (lane < NC) out[(size_t)r * NC + lane] = logit - m - ls;
    }
}

// ---------------- launch ----------------

extern "C" void kernel_launch(void* const* d_in, const int* in_sizes, int n_in,
                              void* d_out, int out_size, void* d_ws, size_t ws_size,
                              hipStream_t stream) {
    const float* x  = (const float*)d_in[0];
    const int*   ei = (const int*)d_in[1];
    const float* w0 = (const float*)d_in[2];
    const float* b0 = (const float*)d_in[3];
    const float* cw = (const float*)d_in[4];
    const float* w1 = (const float*)d_in[5];
    const float* b1 = (const float*)d_in[6];
    float* out = (float*)d_out;

    const int* src = ei;
    const int* dst = ei + NE;

    float* h    = (float*)d_ws;                 // NN*NH
    float* h0   = h  + (size_t)NN * NH;         // NN*NH
    float* z    = h0 + (size_t)NN * NH;         // NN*NH
    float* dinv = z  + (size_t)NN * NH;         // NN
    int* deg    = (int*)(dinv + NN);            // NN
    int* rp     = deg + NN;                     // NN+1
    int* cursor = rp + NN + 1;                  // NN
    int* col    = cursor + NN;                  // NE
    float* val  = (float*)(col + NE);           // NE

    hipMemsetAsync(deg, 0, NN * sizeof(int), stream);
    count_kernel<<<(NE + 255) / 256, 256, 0, stream>>>(dst, deg);
    dinv_kernel<<<(NN + 255) / 256, 256, 0, stream>>>(deg, dinv);
    scan_kernel<<<1, 1024, 0, stream>>>(deg, rp);
    hipMemcpyAsync(cursor, rp, NN * sizeof(int), hipMemcpyDeviceToDevice, stream);
    fill_kernel<<<(NE + 255) / 256, 256, 0, stream>>>(src, dst, dinv, cursor, col, val);

    gemm_in<<<NN / 32, 256, 0, stream>>>(x, w0, b0, h, h0);
    for (int l = 0; l < NL; ++l) {
        float beta = logf(0.5f / (float)(l + 1) + 1.0f);
        agg_kernel<<<NN, 128, 0, stream>>>(h, h0, dinv, rp, col, val, z);
        gemm_conv<<<NN / 32, 256, 0, stream>>>(z, cw + (size_t)l * NH * NH, h, beta);
    }
    out_kernel<<<2048, 256, 0, stream>>>(h, w1, b1, out);
}

// Round 4
// 2106.864 us; speedup vs baseline: 1.4278x; 1.4278x over previous
//
#include <hip/hip_runtime.h>
#include <math.h>

#define NN 100000
#define NE 1600000
#define NF 500
#define NH 128
#define NC 47
#define NL 8

typedef __attribute__((ext_vector_type(8))) __bf16 bf16x8;
typedef __attribute__((ext_vector_type(4))) float f32x4;

// ---------------- graph preprocessing ----------------

__global__ void count_kernel(const int* __restrict__ dst, int* __restrict__ deg) {
    int e = blockIdx.x * 256 + threadIdx.x;
    if (e < NE) atomicAdd(&deg[dst[e]], 1);
}

__global__ void dinv_kernel(const int* __restrict__ deg, float* __restrict__ dinv) {
    int i = blockIdx.x * 256 + threadIdx.x;
    if (i < NN) dinv[i] = rsqrtf((float)(deg[i] + 1));  // +1 self loop
}

// block-local exclusive scan of deg into rp, block totals into bsum
__global__ __launch_bounds__(256) void scan_local(const int* __restrict__ deg,
                                                  int* __restrict__ rp,
                                                  int* __restrict__ bsum) {
    int b = blockIdx.x, t = threadIdx.x;
    int i = b * 256 + t;
    int v = (i < NN) ? deg[i] : 0;
    int lane = t & 63, w = t >> 6;
    int sv = v;
    #pragma unroll
    for (int off = 1; off < 64; off <<= 1) {
        int u = __shfl_up(sv, off);
        if (lane >= off) sv += u;
    }
    __shared__ int wsum[4];
    if (lane == 63) wsum[w] = sv;
    __syncthreads();
    int add = 0;
    #pragma unroll
    for (int j = 0; j < 4; ++j) if (j < w) add += wsum[j];
    if (i < NN) rp[i] = add + sv - v;       // block-local exclusive
    if (t == 255) bsum[b] = add + sv;       // block total
}

__global__ __launch_bounds__(512) void scan_bsum(const int* __restrict__ bsum,
                                                 int* __restrict__ boff) {
    __shared__ int s[512];
    int t = threadIdx.x;
    int v = (t < 391) ? bsum[t] : 0;
    s[t] = v;
    __syncthreads();
    for (int off = 1; off < 512; off <<= 1) {
        int u = (t >= off) ? s[t - off] : 0;
        __syncthreads();
        s[t] += u;
        __syncthreads();
    }
    if (t < 391) boff[t] = s[t] - v;        // exclusive
    if (t == 390) boff[391] = s[390];       // grand total
}

__global__ void addoff_kernel(int* __restrict__ rp, int* __restrict__ cursor,
                              const int* __restrict__ boff) {
    int b = blockIdx.x, t = threadIdx.x;
    int i = b * 256 + t;
    if (i < NN) {
        int v = rp[i] + boff[b];
        rp[i] = v;
        cursor[i] = v;
    }
    if (i == NN) rp[NN] = boff[391];
}

__global__ void fill_kernel(const int* __restrict__ src, const int* __restrict__ dst,
                            const float* __restrict__ dinv, int* __restrict__ cursor,
                            int* __restrict__ col, float* __restrict__ val) {
    int e = blockIdx.x * 256 + threadIdx.x;
    if (e < NE) {
        int s = src[e], d = dst[e];
        int pos = atomicAdd(&cursor[d], 1);
        col[pos] = s;
        val[pos] = dinv[s] * dinv[d];
    }
}

// ---------------- aggregation: z = 0.9 * (norm-adj @ h) + 0.1 * h0 ----------------

__global__ __launch_bounds__(128) void agg_kernel(const float* __restrict__ h,
                                                  const float* __restrict__ h0,
                                                  const float* __restrict__ dinv,
                                                  const int* __restrict__ rp,
                                                  const int* __restrict__ col,
                                                  const float* __restrict__ val,
                                                  float* __restrict__ z) {
    int i = blockIdx.x;
    int t = threadIdx.x;
    float di = dinv[i];
    float a0 = di * di * h[(size_t)i * NH + t];  // self loop
    float a1 = 0.f, a2 = 0.f, a3 = 0.f;
    int e0 = rp[i], e1 = rp[i + 1];
    int e = e0;
    for (; e + 4 <= e1; e += 4) {
        int c0 = col[e], c1 = col[e + 1], c2 = col[e + 2], c3 = col[e + 3];
        float v0 = val[e], v1 = val[e + 1], v2 = val[e + 2], v3 = val[e + 3];
        a0 = fmaf(v0, h[(size_t)c0 * NH + t], a0);
        a1 = fmaf(v1, h[(size_t)c1 * NH + t], a1);
        a2 = fmaf(v2, h[(size_t)c2 * NH + t], a2);
        a3 = fmaf(v3, h[(size_t)c3 * NH + t], a3);
    }
    for (; e < e1; ++e) a0 = fmaf(val[e], h[(size_t)col[e] * NH + t], a0);
    float acc = (a0 + a1) + (a2 + a3);
    z[(size_t)i * NH + t] = 0.9f * acc + 0.1f * h0[(size_t)i * NH + t];
}

// ---------------- bf16 MFMA GEMMs ----------------

__device__ inline bf16x8 cvt8(float4 a, float4 b) {
    bf16x8 r;
    r[0] = (__bf16)a.x; r[1] = (__bf16)a.y; r[2] = (__bf16)a.z; r[3] = (__bf16)a.w;
    r[4] = (__bf16)b.x; r[5] = (__bf16)b.y; r[6] = (__bf16)b.z; r[7] = (__bf16)b.w;
    return r;
}

// h = relu(x @ w0 + b0); h0 = h.  Tile 128 rows x 128 cols, K padded 500->512.
__global__ __launch_bounds__(256) void gemm_in(const float* __restrict__ x,
                                               const float* __restrict__ w0,
                                               const float* __restrict__ b0,
                                               float* __restrict__ h,
                                               float* __restrict__ h0v) {
    __shared__ __align__(16) unsigned short ldsA[16384];   // 128 rows x 128 k, swizzled
    __shared__ __align__(16) unsigned short ldsBT[16384];  // 128 n x 128 k, swizzled
    int tid = threadIdx.x;
    int rbase = blockIdx.x * 128;
    int lane = tid & 63, wm = tid >> 6;
    int l15 = lane & 15, lk = (lane >> 4) * 8;

    f32x4 acc[2][8] = {};
    for (int kb = 0; kb < 512; kb += 128) {
        __syncthreads();
        // stage A (x -> bf16, swizzled)
        #pragma unroll
        for (int i = 0; i < 8; ++i) {
            int c = tid + 256 * i;           // 2048 chunks of 8 elems
            int row = c >> 4, slot = c & 15;
            int gr = min(rbase + row, NN - 1);
            int k4a = kb + slot * 8;
            const float* xp = x + (size_t)gr * NF + k4a;
            float4 va = (k4a < NF) ? *(const float4*)xp : float4{0, 0, 0, 0};
            float4 vb = (k4a + 4 < NF) ? *(const float4*)(xp + 4) : float4{0, 0, 0, 0};
            int boff = row * 256 + ((slot * 16) ^ ((row & 7) << 4));
            *(bf16x8*)((char*)ldsA + boff) = cvt8(va, vb);
        }
        // stage BT (w0 transposed -> bf16, swizzled)
        #pragma unroll
        for (int i = 0; i < 16; ++i) {
            int c = tid + 256 * i;           // 4096 float4s
            int k = c >> 5, n0 = (c & 31) * 4;
            int kg = kb + k;
            float4 w4 = (kg < NF) ? *(const float4*)(w0 + (size_t)kg * NH + n0)
                                  : float4{0, 0, 0, 0};
            #pragma unroll
            for (int j = 0; j < 4; ++j) {
                int n = n0 + j;
                *(__bf16*)((char*)ldsBT + n * 256 + ((k * 2) ^ ((n & 7) << 4))) =
                    (__bf16)(&w4.x)[j];
            }
        }
        __syncthreads();
        #pragma unroll
        for (int kf = 0; kf < 4; ++kf) {
            int k0 = kf * 32 + lk;
            bf16x8 a[2], b[8];
            #pragma unroll
            for (int mi = 0; mi < 2; ++mi) {
                int row = wm * 32 + mi * 16 + l15;
                a[mi] = *(const bf16x8*)((char*)ldsA + row * 256 +
                                         ((k0 * 2) ^ ((row & 7) << 4)));
            }
            #pragma unroll
            for (int nf = 0; nf < 8; ++nf) {
                int n = nf * 16 + l15;
                b[nf] = *(const bf16x8*)((char*)ldsBT + n * 256 +
                                         ((k0 * 2) ^ ((n & 7) << 4)));
            }
            #pragma unroll
            for (int mi = 0; mi < 2; ++mi)
                #pragma unroll
                for (int nf = 0; nf < 8; ++nf)
                    acc[mi][nf] = __builtin_amdgcn_mfma_f32_16x16x32_bf16(
                        a[mi], b[nf], acc[mi][nf], 0, 0, 0);
        }
    }
    // epilogue: bias + relu, write h and h0
    #pragma unroll
    for (int mi = 0; mi < 2; ++mi) {
        #pragma unroll
        for (int nf = 0; nf < 8; ++nf) {
            int colg = nf * 16 + l15;
            float bias = b0[colg];
            #pragma unroll
            for (int r = 0; r < 4; ++r) {
                int row = rbase + wm * 32 + mi * 16 + (lane >> 4) * 4 + r;
                if (row < NN) {
                    float o = fmaxf(acc[mi][nf][r] + bias, 0.f);
                    h[(size_t)row * NH + colg] = o;
                    h0v[(size_t)row * NH + colg] = o;
                }
            }
        }
    }
}

// h = relu((1-beta)*z + beta*(z @ W)).  Tile 128 x 128, K = 128 staged once.
__global__ __launch_bounds__(256) void gemm_conv(const float* __restrict__ z,
                                                 const float* __restrict__ W,
                                                 float* __restrict__ h, float beta) {
    __shared__ __align__(16) unsigned short ldsA[16384];
    __shared__ __align__(16) unsigned short ldsBT[16384];
    int tid = threadIdx.x;
    int rbase = blockIdx.x * 128;
    int lane = tid & 63, wm = tid >> 6;
    int l15 = lane & 15, lk = (lane >> 4) * 8;

    // stage A (z -> bf16, swizzled)
    #pragma unroll
    for (int i = 0; i < 8; ++i) {
        int c = tid + 256 * i;
        int row = c >> 4, slot = c & 15;
        int gr = min(rbase + row, NN - 1);
        const float4* zp = (const float4*)(z + (size_t)gr * NH + slot * 8);
        int boff = row * 256 + ((slot * 16) ^ ((row & 7) << 4));
        *(bf16x8*)((char*)ldsA + boff) = cvt8(zp[0], zp[1]);
    }
    // stage BT (W transposed -> bf16, swizzled)
    #pragma unroll
    for (int i = 0; i < 16; ++i) {
        int c = tid + 256 * i;
        int k = c >> 5, n0 = (c & 31) * 4;
        float4 w4 = *(const float4*)(W + (size_t)k * NH + n0);
        #pragma unroll
        for (int j = 0; j < 4; ++j) {
            int n = n0 + j;
            *(__bf16*)((char*)ldsBT + n * 256 + ((k * 2) ^ ((n & 7) << 4))) =
                (__bf16)(&w4.x)[j];
        }
    }
    __syncthreads();

    f32x4 acc[2][8] = {};
    #pragma unroll
    for (int kf = 0; kf < 4; ++kf) {
        int k0 = kf * 32 + lk;
        bf16x8 a[2], b[8];
        #pragma unroll
        for (int mi = 0; mi < 2; ++mi) {
            int row = wm * 32 + mi * 16 + l15;
            a[mi] = *(const bf16x8*)((char*)ldsA + row * 256 +
                                     ((k0 * 2) ^ ((row & 7) << 4)));
        }
        #pragma unroll
        for (int nf = 0; nf < 8; ++nf) {
            int n = nf * 16 + l15;
            b[nf] = *(const bf16x8*)((char*)ldsBT + n * 256 +
                                     ((k0 * 2) ^ ((n & 7) << 4)));
        }
        #pragma unroll
        for (int mi = 0; mi < 2; ++mi)
            #pragma unroll
            for (int nf = 0; nf < 8; ++nf)
                acc[mi][nf] = __builtin_amdgcn_mfma_f32_16x16x32_bf16(
                    a[mi], b[nf], acc[mi][nf], 0, 0, 0);
    }

    float ob = 1.0f - beta;
    #pragma unroll
    for (int mi = 0; mi < 2; ++mi) {
        #pragma unroll
        for (int nf = 0; nf < 8; ++nf) {
            int colg = nf * 16 + l15;
            #pragma unroll
            for (int r = 0; r < 4; ++r) {
                int row = rbase + wm * 32 + mi * 16 + (lane >> 4) * 4 + r;
                if (row < NN) {
                    float zv = z[(size_t)row * NH + colg];
                    h[(size_t)row * NH + colg] =
                        fmaxf(ob * zv + beta * acc[mi][nf][r], 0.f);
                }
            }
        }
    }
}

// logits = h @ w1 + b1 ; out = log_softmax(logits)
__global__ __launch_bounds__(256) void out_kernel(const float* __restrict__ h,
                                                  const float* __restrict__ w1,
                                                  const float* __restrict__ b1,
                                                  float* __restrict__ out) {
    __shared__ float wl[NH * NC];
    int tid = threadIdx.x;
    for (int i = tid; i < NH * NC; i += 256) wl[i] = w1[i];
    __syncthreads();
    int wave = tid >> 6, lane = tid & 63;
    for (int r = blockIdx.x * 4 + wave; r < NN; r += gridDim.x * 4) {
        const float* hr = h + (size_t)r * NH;
        float a0 = 0.f, a1 = 0.f, a2 = 0.f, a3 = 0.f;
        float bias = 0.f;
        if (lane < NC) {
            bias = b1[lane];
            for (int k = 0; k < NH; k += 4) {
                a0 = fmaf(hr[k], wl[k * NC + lane], a0);
                a1 = fmaf(hr[k + 1], wl[(k + 1) * NC + lane], a1);
                a2 = fmaf(hr[k + 2], wl[(k + 2) * NC + lane], a2);
                a3 = fmaf(hr[k + 3], wl[(k + 3) * NC + lane], a3);
            }
        }
        float logit = (lane < NC) ? (bias + (a0 + a1) + (a2 + a3)) : -INFINITY;
        float m = logit;
        #pragma unroll
        for (int off = 32; off > 0; off >>= 1) m = fmaxf(m, __shfl_xor(m, off));
        float e = expf(logit - m);
        float ssum = e;
        #pragma unroll
        for (int off = 32; off > 0; off >>= 1) ssum += __shfl_xor(ssum, off);
        float ls = logf(ssum);
        if (lane < NC) out[(size_t)r * NC + lane] = logit - m - ls;
    }
}

// ---------------- launch ----------------

extern "C" void kernel_launch(void* const* d_in, const int* in_sizes, int n_in,
                              void* d_out, int out_size, void* d_ws, size_t ws_size,
                              hipStream_t stream) {
    const float* x  = (const float*)d_in[0];
    const int*   ei = (const int*)d_in[1];
    const float* w0 = (const float*)d_in[2];
    const float* b0 = (const float*)d_in[3];
    const float* cw = (const float*)d_in[4];
    const float* w1 = (const float*)d_in[5];
    const float* b1 = (const float*)d_in[6];
    float* out = (float*)d_out;

    const int* src = ei;
    const int* dst = ei + NE;

    float* h    = (float*)d_ws;                 // NN*NH
    float* h0   = h  + (size_t)NN * NH;         // NN*NH
    float* z    = h0 + (size_t)NN * NH;         // NN*NH
    float* dinv = z  + (size_t)NN * NH;         // NN
    int* deg    = (int*)(dinv + NN);            // NN
    int* rp     = deg + NN;                     // NN+1
    int* cursor = rp + NN + 1;                  // NN
    int* bsum   = cursor + NN;                  // 392
    int* boff   = bsum + 392;                   // 392
    int* col    = boff + 392;                   // NE
    float* val  = (float*)(col + NE);           // NE

    hipMemsetAsync(deg, 0, NN * sizeof(int), stream);
    count_kernel<<<(NE + 255) / 256, 256, 0, stream>>>(dst, deg);
    dinv_kernel<<<391, 256, 0, stream>>>(deg, dinv);
    scan_local<<<391, 256, 0, stream>>>(deg, rp, bsum);
    scan_bsum<<<1, 512, 0, stream>>>(bsum, boff);
    addoff_kernel<<<391, 256, 0, stream>>>(rp, cursor, boff);
    fill_kernel<<<(NE + 255) / 256, 256, 0, stream>>>(src, dst, dinv, cursor, col, val);

    gemm_in<<<782, 256, 0, stream>>>(x, w0, b0, h, h0);
    for (int l = 0; l < NL; ++l) {
        float beta = logf(0.5f / (float)(l + 1) + 1.0f);
        agg_kernel<<<NN, 128, 0, stream>>>(h, h0, dinv, rp, col, val, z);
        gemm_conv<<<782, 256, 0, stream>>>(z, cw + (size_t)l * NH * NH, h, beta);
    }
    out_kernel<<<2048, 256, 0, stream>>>(h, w1, b1, out);
}

// Round 15
// 1635.876 us; speedup vs baseline: 1.8388x; 1.2879x over previous
//
#include <hip/hip_runtime.h>
#include <math.h>

#define NN 100000
#define NE 1600000
#define NF 500
#define NH 128
#define NC 47
#define NL 8

typedef __attribute__((ext_vector_type(8))) __bf16 bf16x8;
typedef __attribute__((ext_vector_type(4))) float f32x4;

// ---------------- graph preprocessing ----------------

__global__ void count_kernel(const int* __restrict__ dst, int* __restrict__ deg) {
    int e = blockIdx.x * 256 + threadIdx.x;
    if (e < NE) atomicAdd(&deg[dst[e]], 1);
}

__global__ void dinv_kernel(const int* __restrict__ deg, float* __restrict__ dinv) {
    int i = blockIdx.x * 256 + threadIdx.x;
    if (i < NN) dinv[i] = rsqrtf((float)(deg[i] + 1));  // +1 self loop
}

__global__ __launch_bounds__(256) void scan_local(const int* __restrict__ deg,
                                                  int* __restrict__ rp,
                                                  int* __restrict__ bsum) {
    int b = blockIdx.x, t = threadIdx.x;
    int i = b * 256 + t;
    int v = (i < NN) ? deg[i] : 0;
    int lane = t & 63, w = t >> 6;
    int sv = v;
    #pragma unroll
    for (int off = 1; off < 64; off <<= 1) {
        int u = __shfl_up(sv, off);
        if (lane >= off) sv += u;
    }
    __shared__ int wsum[4];
    if (lane == 63) wsum[w] = sv;
    __syncthreads();
    int add = 0;
    #pragma unroll
    for (int j = 0; j < 4; ++j) if (j < w) add += wsum[j];
    if (i < NN) rp[i] = add + sv - v;
    if (t == 255) bsum[b] = add + sv;
}

__global__ __launch_bounds__(512) void scan_bsum(const int* __restrict__ bsum,
                                                 int* __restrict__ boff) {
    __shared__ int s[512];
    int t = threadIdx.x;
    int v = (t < 391) ? bsum[t] : 0;
    s[t] = v;
    __syncthreads();
    for (int off = 1; off < 512; off <<= 1) {
        int u = (t >= off) ? s[t - off] : 0;
        __syncthreads();
        s[t] += u;
        __syncthreads();
    }
    if (t < 391) boff[t] = s[t] - v;
    if (t == 390) boff[391] = s[390];
}

__global__ void addoff_kernel(int* __restrict__ rp, int* __restrict__ cursor,
                              const int* __restrict__ boff) {
    int b = blockIdx.x, t = threadIdx.x;
    int i = b * 256 + t;
    if (i < NN) {
        int v = rp[i] + boff[b];
        rp[i] = v;
        cursor[i] = v;
    }
    if (i == NN) rp[NN] = boff[391];
}

__global__ void fill_kernel(const int* __restrict__ src, const int* __restrict__ dst,
                            const float* __restrict__ dinv, int* __restrict__ cursor,
                            int* __restrict__ col, float* __restrict__ val) {
    int e = blockIdx.x * 256 + threadIdx.x;
    if (e < NE) {
        int s = src[e], d = dst[e];
        int pos = atomicAdd(&cursor[d], 1);
        col[pos] = s;
        val[pos] = dinv[s] * dinv[d];
    }
}

// ---------------- dtype prep ----------------

__device__ inline bf16x8 cvt8(float4 a, float4 b) {
    bf16x8 r;
    r[0] = (__bf16)a.x; r[1] = (__bf16)a.y; r[2] = (__bf16)a.z; r[3] = (__bf16)a.w;
    r[4] = (__bf16)b.x; r[5] = (__bf16)b.y; r[6] = (__bf16)b.z; r[7] = (__bf16)b.w;
    return r;
}

// w0 [500][128] -> w0T bf16 [128][512] (transposed, padded); cw [8][128][128] -> cwT [8][128n][128k]
__global__ __launch_bounds__(256) void cvt_w(const float* __restrict__ w0,
                                             const float* __restrict__ cw,
                                             __bf16* __restrict__ w0T,
                                             __bf16* __restrict__ cwT) {
    int idx = blockIdx.x * 256 + threadIdx.x;
    if (idx < 128 * 512) {
        int n = idx >> 9, k = idx & 511;
        w0T[idx] = (k < NF) ? (__bf16)w0[(size_t)k * NH + n] : (__bf16)0.f;
    } else if (idx < 128 * 512 + 8 * 128 * 128) {
        int j = idx - 128 * 512;
        int l = j >> 14, r = j & 16383;
        int n = r >> 7, k = r & 127;
        cwT[j] = (__bf16)cw[(size_t)l * 16384 + k * NH + n];
    }
}

// ---------------- aggregation: zb = 0.9*(A_norm @ h) + 0.1*h0  (bf16 gather, f32 accum) ----------------

__global__ __launch_bounds__(128) void agg_kernel(const __bf16* __restrict__ hb,
                                                  const __bf16* __restrict__ h0b,
                                                  const float* __restrict__ dinv,
                                                  const int* __restrict__ rp,
                                                  const int* __restrict__ col,
                                                  const float* __restrict__ val,
                                                  __bf16* __restrict__ zb) {
    int i = blockIdx.x;
    int t = threadIdx.x;
    float di = dinv[i];
    float a0 = di * di * (float)hb[(size_t)i * NH + t];  // self loop
    float a1 = 0.f, a2 = 0.f, a3 = 0.f;
    int e1 = rp[i + 1];
    int e = rp[i];
    for (; e + 4 <= e1; e += 4) {
        int c0 = col[e], c1 = col[e + 1], c2 = col[e + 2], c3 = col[e + 3];
        float v0 = val[e], v1 = val[e + 1], v2 = val[e + 2], v3 = val[e + 3];
        a0 = fmaf(v0, (float)hb[(size_t)c0 * NH + t], a0);
        a1 = fmaf(v1, (float)hb[(size_t)c1 * NH + t], a1);
        a2 = fmaf(v2, (float)hb[(size_t)c2 * NH + t], a2);
        a3 = fmaf(v3, (float)hb[(size_t)c3 * NH + t], a3);
    }
    for (; e < e1; ++e) a0 = fmaf(val[e], (float)hb[(size_t)col[e] * NH + t], a0);
    float acc = (a0 + a1) + (a2 + a3);
    zb[(size_t)i * NH + t] = (__bf16)(0.9f * acc + 0.1f * (float)h0b[(size_t)i * NH + t]);
}

// ---------------- bf16 MFMA GEMMs (K-step 64, 32KB LDS, swizzled both sides) ----------------

// hb = relu(x @ w0 + b0) via bf16; h0b = hb.  x f32 [NN][500] (cvt in staging), w0T bf16 [128][512].
__global__ __launch_bounds__(256, 3) void gemm_in(const float* __restrict__ x,
                                                  const __bf16* __restrict__ w0T,
                                                  const float* __restrict__ b0,
                                                  __bf16* __restrict__ hb,
                                                  __bf16* __restrict__ h0b) {
    __shared__ __align__(16) char ldsA[16384];   // 128 rows x 64 k x bf16
    __shared__ __align__(16) char ldsB[16384];   // 128 n   x 64 k x bf16
    int tid = threadIdx.x;
    int rbase = blockIdx.x * 128;
    int lane = tid & 63, wm = tid >> 6, wr = wm >> 1, wc = wm & 1;
    int l15 = lane & 15, lkb = (lane >> 4) * 16;   // byte k-offset ((lane>>4)*8 elems)

    f32x4 acc[4][4] = {};
    for (int kb = 0; kb < 512; kb += 64) {
        __syncthreads();
        #pragma unroll
        for (int i = 0; i < 4; ++i) {
            int c = tid + 256 * i;               // 1024 chunks: 128 rows x 8 slots
            int r = c >> 3, s = c & 7;
            int gr = min(rbase + r, NN - 1);
            int k4a = kb + s * 8;
            const float* xp = x + (size_t)gr * NF + k4a;
            float4 fa = (k4a < NF) ? *(const float4*)xp : float4{0, 0, 0, 0};
            float4 fb = (k4a + 4 < NF) ? *(const float4*)(xp + 4) : float4{0, 0, 0, 0};
            bf16x8 va = cvt8(fa, fb);
            bf16x8 vb = *(const bf16x8*)(w0T + (size_t)r * 512 + k4a);
            int sw = (s * 16) ^ ((r & 7) << 4);
            *(bf16x8*)(ldsA + r * 128 + sw) = va;
            *(bf16x8*)(ldsB + r * 128 + sw) = vb;
        }
        __syncthreads();
        #pragma unroll
        for (int kf = 0; kf < 2; ++kf) {
            int k0b = kf * 64 + lkb;
            bf16x8 a[4], b[4];
            #pragma unroll
            for (int mi = 0; mi < 4; ++mi) {
                int row = wr * 64 + mi * 16 + l15;
                a[mi] = *(const bf16x8*)(ldsA + row * 128 + (k0b ^ ((row & 7) << 4)));
            }
            #pragma unroll
            for (int nf = 0; nf < 4; ++nf) {
                int n = wc * 64 + nf * 16 + l15;
                b[nf] = *(const bf16x8*)(ldsB + n * 128 + (k0b ^ ((n & 7) << 4)));
            }
            #pragma unroll
            for (int mi = 0; mi < 4; ++mi)
                #pragma unroll
                for (int nf = 0; nf < 4; ++nf)
                    acc[mi][nf] = __builtin_amdgcn_mfma_f32_16x16x32_bf16(
                        a[mi], b[nf], acc[mi][nf], 0, 0, 0);
        }
    }
    int rq = (lane >> 4) * 4;
    #pragma unroll
    for (int nf = 0; nf < 4; ++nf) {
        int colg = wc * 64 + nf * 16 + l15;
        float bias = b0[colg];
        #pragma unroll
        for (int mi = 0; mi < 4; ++mi) {
            #pragma unroll
            for (int r = 0; r < 4; ++r) {
                int row = rbase + wr * 64 + mi * 16 + rq + r;
                if (row < NN) {
                    __bf16 o = (__bf16)fmaxf(acc[mi][nf][r] + bias, 0.f);
                    hb[(size_t)row * NH + colg] = o;
                    h0b[(size_t)row * NH + colg] = o;
                }
            }
        }
    }
}

// hb = relu((1-beta)*zb + beta*(zb @ W^T)).  zb [NN][128] bf16, WT [128n][128k] bf16.
__global__ __launch_bounds__(256, 3) void gemm_conv(const __bf16* __restrict__ zb,
                                                    const __bf16* __restrict__ WT,
                                                    __bf16* __restrict__ hb, float beta) {
    __shared__ __align__(16) char ldsA[16384];
    __shared__ __align__(16) char ldsB[16384];
    int tid = threadIdx.x;
    int rbase = blockIdx.x * 128;
    int lane = tid & 63, wm = tid >> 6, wr = wm >> 1, wc = wm & 1;
    int l15 = lane & 15, lkb = (lane >> 4) * 16;

    f32x4 acc[4][4] = {};
    for (int kb = 0; kb < 128; kb += 64) {
        __syncthreads();
        #pragma unroll
        for (int i = 0; i < 4; ++i) {
            int c = tid + 256 * i;
            int r = c >> 3, s = c & 7;
            int gr = min(rbase + r, NN - 1);
            bf16x8 va = *(const bf16x8*)(zb + (size_t)gr * NH + kb + s * 8);
            bf16x8 vb = *(const bf16x8*)(WT + (size_t)r * NH + kb + s * 8);
            int sw = (s * 16) ^ ((r & 7) << 4);
            *(bf16x8*)(ldsA + r * 128 + sw) = va;
            *(bf16x8*)(ldsB + r * 128 + sw) = vb;
        }
        __syncthreads();
        #pragma unroll
        for (int kf = 0; kf < 2; ++kf) {
            int k0b = kf * 64 + lkb;
            bf16x8 a[4], b[4];
            #pragma unroll
            for (int mi = 0; mi < 4; ++mi) {
                int row = wr * 64 + mi * 16 + l15;
                a[mi] = *(const bf16x8*)(ldsA + row * 128 + (k0b ^ ((row & 7) << 4)));
            }
            #pragma unroll
            for (int nf = 0; nf < 4; ++nf) {
                int n = wc * 64 + nf * 16 + l15;
                b[nf] = *(const bf16x8*)(ldsB + n * 128 + (k0b ^ ((n & 7) << 4)));
            }
            #pragma unroll
            for (int mi = 0; mi < 4; ++mi)
                #pragma unroll
                for (int nf = 0; nf < 4; ++nf)
                    acc[mi][nf] = __builtin_amdgcn_mfma_f32_16x16x32_bf16(
                        a[mi], b[nf], acc[mi][nf], 0, 0, 0);
        }
    }
    float ob = 1.0f - beta;
    int rq = (lane >> 4) * 4;
    #pragma unroll
    for (int nf = 0; nf < 4; ++nf) {
        int colg = wc * 64 + nf * 16 + l15;
        #pragma unroll
        for (int mi = 0; mi < 4; ++mi) {
            #pragma unroll
            for (int r = 0; r < 4; ++r) {
                int row = rbase + wr * 64 + mi * 16 + rq + r;
                if (row < NN) {
                    float zv = (float)zb[(size_t)row * NH + colg];
                    hb[(size_t)row * NH + colg] =
                        (__bf16)fmaxf(ob * zv + beta * acc[mi][nf][r], 0.f);
                }
            }
        }
    }
}

// logits = hb @ w1 + b1 ; out = log_softmax(logits)
__global__ __launch_bounds__(256) void out_kernel(const __bf16* __restrict__ hb,
                                                  const float* __restrict__ w1,
                                                  const float* __restrict__ b1,
                                                  float* __restrict__ out) {
    __shared__ float wl[NH * NC];
    int tid = threadIdx.x;
    for (int i = tid; i < NH * NC; i += 256) wl[i] = w1[i];
    __syncthreads();
    int wave = tid >> 6, lane = tid & 63;
    for (int r = blockIdx.x * 4 + wave; r < NN; r += gridDim.x * 4) {
        const __bf16* hr = hb + (size_t)r * NH;
        float a0 = 0.f, a1 = 0.f, a2 = 0.f, a3 = 0.f;
        float bias = 0.f;
        if (lane < NC) {
            bias = b1[lane];
            for (int k = 0; k < NH; k += 4) {
                a0 = fmaf((float)hr[k],     wl[k * NC + lane], a0);
                a1 = fmaf((float)hr[k + 1], wl[(k + 1) * NC + lane], a1);
                a2 = fmaf((float)hr[k + 2], wl[(k + 2) * NC + lane], a2);
                a3 = fmaf((float)hr[k + 3], wl[(k + 3) * NC + lane], a3);
            }
        }
        float logit = (lane < NC) ? (bias + (a0 + a1) + (a2 + a3)) : -INFINITY;
        float m = logit;
        #pragma unroll
        for (int off = 32; off > 0; off >>= 1) m = fmaxf(m, __shfl_xor(m, off));
        float e = expf(logit - m);
        float ssum = e;
        #pragma unroll
        for (int off = 32; off > 0; off >>= 1) ssum += __shfl_xor(ssum, off);
        float ls = logf(ssum);
        if (lane < NC) out[(size_t)r * NC + lane] = logit - m - ls;
    }
}

// ---------------- launch ----------------

extern "C" void kernel_launch(void* const* d_in, const int* in_sizes, int n_in,
                              void* d_out, int out_size, void* d_ws, size_t ws_size,
                              hipStream_t stream) {
    const float* x  = (const float*)d_in[0];
    const int*   ei = (const int*)d_in[1];
    const float* w0 = (const float*)d_in[2];
    const float* b0 = (const float*)d_in[3];
    const float* cw = (const float*)d_in[4];
    const float* w1 = (const float*)d_in[5];
    const float* b1 = (const float*)d_in[6];
    float* out = (float*)d_out;

    const int* src = ei;
    const int* dst = ei + NE;

    char* p = (char*)d_ws;
    __bf16* hb  = (__bf16*)p;  p += (size_t)NN * NH * 2;      // 25.6 MB
    __bf16* h0b = (__bf16*)p;  p += (size_t)NN * NH * 2;      // 25.6 MB
    __bf16* zb  = (__bf16*)p;  p += (size_t)NN * NH * 2;      // 25.6 MB
    __bf16* w0T = (__bf16*)p;  p += 128 * 512 * 2;
    __bf16* cwT = (__bf16*)p;  p += 8 * 128 * 128 * 2;
    float* dinv = (float*)p;   p += (size_t)NN * 4;
    int* deg    = (int*)p;     p += (size_t)NN * 4;
    int* rp     = (int*)p;     p += (size_t)(NN + 1) * 4;
    int* cursor = (int*)p;     p += (size_t)NN * 4;
    int* bsum   = (int*)p;     p += 392 * 4;
    int* boff   = (int*)p;     p += 392 * 4;
    int* col    = (int*)p;     p += (size_t)NE * 4;
    float* val  = (float*)p;

    // graph preprocessing
    hipMemsetAsync(deg, 0, NN * sizeof(int), stream);
    count_kernel<<<(NE + 255) / 256, 256, 0, stream>>>(dst, deg);
    dinv_kernel<<<391, 256, 0, stream>>>(deg, dinv);
    scan_local<<<391, 256, 0, stream>>>(deg, rp, bsum);
    scan_bsum<<<1, 512, 0, stream>>>(bsum, boff);
    addoff_kernel<<<391, 256, 0, stream>>>(rp, cursor, boff);
    fill_kernel<<<(NE + 255) / 256, 256, 0, stream>>>(src, dst, dinv, cursor, col, val);

    // weight prep
    cvt_w<<<768, 256, 0, stream>>>(w0, cw, w0T, cwT);

    gemm_in<<<782, 256, 0, stream>>>(x, w0T, b0, hb, h0b);
    for (int l = 0; l < NL; ++l) {
        float beta = logf(0.5f / (float)(l + 1) + 1.0f);
        agg_kernel<<<NN, 128, 0, stream>>>(hb, h0b, dinv, rp, col, val, zb);
        gemm_conv<<<782, 256, 0, stream>>>(zb, cwT + (size_t)l * 128 * 128, hb, beta);
    }
    out_kernel<<<2048, 256, 0, stream>>>(hb, w1, b1, out);
}